// Round 3
// baseline (494.608 us; speedup 1.0000x reference)
//
#include <hip/hip_runtime.h>
#include <cstdint>
#include <cstddef>

typedef unsigned short u16;
typedef __attribute__((ext_vector_type(8))) short bhalf8;   // 8 x bf16 (4 VGPRs)
typedef __attribute__((ext_vector_type(4))) float fx4;      // MFMA 16x16 accumulator
typedef __attribute__((ext_vector_type(4))) unsigned short u16x4;

#define T_SEQ 2048
#define NHEAD 25
#define QKV_LD 4864   // padded 3C row stride (4800 -> 38*128) so 128-wide N-tiles divide evenly

static __device__ __forceinline__ u16 f2bf(float f) {
  union { float f; uint32_t u; } v; v.f = f;
  uint32_t r = (v.u + 0x7FFFu + ((v.u >> 16) & 1u)) >> 16;  // RNE
  return (u16)r;
}

static __device__ __forceinline__ fx4 mfma16(bhalf8 a, bhalf8 b, fx4 c) {
  return __builtin_amdgcn_mfma_f32_16x16x32_bf16(a, b, c, 0, 0, 0);
}

// async global->LDS, 16B per lane. LDS dest: wave-uniform base + lane*16 (linear!).
static __device__ __forceinline__ void async16(const void* g, void* l) {
  __builtin_amdgcn_global_load_lds(
      (__attribute__((address_space(1))) unsigned int*)(void*)g,
      (__attribute__((address_space(3))) unsigned int*)l, 16, 0, 0);
}

// ---------------- convert f32 -> bf16, vectorized (G13) ----------------
__global__ void cvt_bf16_kernel(const float* __restrict__ in, u16* __restrict__ out, int n4) {
  int i = blockIdx.x * 256 + threadIdx.x;
  if (i >= n4) return;
  float4 v = ((const float4*)in)[i];
  u16x4 o;
  o.x = f2bf(v.x); o.y = f2bf(v.y); o.z = f2bf(v.z); o.w = f2bf(v.w);
  ((u16x4*)out)[i] = o;
}

// ------- transpose + convert: in [R][C] f32 -> out [C][R] bf16 (R,C % 32 == 0) -------
__global__ void transp_cvt_kernel(const float* __restrict__ in, u16* __restrict__ out,
                                  int R, int C) {
  __shared__ float tile[32][33];
  int bx = blockIdx.x * 32, by = blockIdx.y * 32;
  int tx = threadIdx.x, ty = threadIdx.y;
  #pragma unroll
  for (int i = 0; i < 32; i += 8)
    tile[ty + i][tx] = in[(size_t)(by + ty + i) * C + bx + tx];
  __syncthreads();
  #pragma unroll
  for (int i = 0; i < 32; i += 8)
    out[(size_t)(bx + ty + i) * R + by + tx] = f2bf(tile[tx][ty + i]);
}

// ---------------- GEMM: C[M,N] = A[M,K] * BT[N,K]^T + bias ----------------
// m97-structure: 128xBN tile, BK=32, 4 waves (2x2), global_load_lds(16B) staging.
// + T1 XCD swizzle (nwg % 8 == 0 for all our launches).
template<int BN, bool OUTF32>
__global__ __launch_bounds__(256)
void gemm_bt_kernel(const u16* __restrict__ A, const u16* __restrict__ BT,
                    const float* __restrict__ bias, void* __restrict__ C,
                    int K, int ldc, int Nreal) {
  constexpr int BM = 128, BK = 32;
  constexpr int NF = BN / 32;                     // frags per wave along N
  constexpr int APASS = (BM * BK) / (256 * 8);    // 2
  constexpr int BPASS = (BN * BK) / (256 * 8);    // 2 (BN=128) or 1 (BN=64)
  __shared__ __align__(16) u16 Al[BM * BK];
  __shared__ __align__(16) u16 Bl[BN * BK];
  const int t = threadIdx.x;
  const int w = t >> 6, l = t & 63, lr = l & 15, lg = l >> 4;
  const int wm = w >> 1, wn = w & 1;

  // XCD-aware swizzle of the linear block id (T1; nwg%8==0 guaranteed here)
  const int nwg = gridDim.x * gridDim.y;
  const int id = blockIdx.y * gridDim.x + blockIdx.x;
  const int qq = nwg >> 3;
  const int swz = (id & 7) * qq + (id >> 3);
  const int bx = swz % gridDim.x, by = swz / gridDim.x;

  const int m0 = by * BM, n0 = bx * BN;

  fx4 acc[4][NF] = {};

  for (int k0 = 0; k0 < K; k0 += BK) {
    #pragma unroll
    for (int p = 0; p < APASS; ++p) {
      int c = t + p * 256;  // 16B chunk id; row = c>>2, col8 = (c&3)*8
      async16(A + (size_t)(m0 + (c >> 2)) * K + k0 + (c & 3) * 8, Al + c * 8);
    }
    #pragma unroll
    for (int p = 0; p < BPASS; ++p) {
      int c = t + p * 256;
      async16(BT + (size_t)(n0 + (c >> 2)) * K + k0 + (c & 3) * 8, Bl + c * 8);
    }
    __syncthreads();  // compiler drains vmcnt before barrier
    bhalf8 af[4], bfr[NF];
    #pragma unroll
    for (int m = 0; m < 4; ++m)
      af[m] = *(const bhalf8*)(Al + (wm * 64 + m * 16 + lr) * BK + lg * 8);
    #pragma unroll
    for (int n = 0; n < NF; ++n)
      bfr[n] = *(const bhalf8*)(Bl + (wn * (BN / 2) + n * 16 + lr) * BK + lg * 8);
    #pragma unroll
    for (int m = 0; m < 4; ++m)
      #pragma unroll
      for (int n = 0; n < NF; ++n)
        acc[m][n] = mfma16(af[m], bfr[n], acc[m][n]);
    __syncthreads();
  }

  // epilogue: C/D layout col=lane&15, row=(lane>>4)*4+reg (m89-verified)
  #pragma unroll
  for (int m = 0; m < 4; ++m)
  #pragma unroll
  for (int n = 0; n < NF; ++n)
  #pragma unroll
  for (int r = 0; r < 4; ++r) {
    int gr = m0 + wm * 64 + m * 16 + lg * 4 + r;
    int gc = n0 + wn * (BN / 2) + n * 16 + lr;
    float bv = (gc < Nreal) ? bias[gc] : 0.0f;
    float v = acc[m][n][r] + bv;
    if constexpr (OUTF32) ((float*)C)[(size_t)gr * ldc + gc] = v;
    else                  ((u16*)C)[(size_t)gr * ldc + gc] = f2bf(v);
  }
}

// ---------------- flash attention, causal, D=64 ----------------
// 8 waves x 16 q-rows = 128 q-rows/block, KBLK=64, double-buffered K/V,
// async16 K staging (XOR-swizzled via pre-swizzled global source),
// reg-staged V with swizzled transpose scatter, ONE barrier per kv-iter.
// Swizzle: 16B slot s of row r holds data slot (s ^ (r&7)).
#define KSWZ(row, slot) (((row) << 6) + ((((slot)) ^ ((row) & 7)) << 3))

__global__ __launch_bounds__(512, 4)
void attn_kernel(const u16* __restrict__ qkv, u16* __restrict__ out) {
  const int qblk = (gridDim.x - 1) - blockIdx.x;  // big blocks first (causal tail)
  const int bh = blockIdx.y;
  const int b = bh / NHEAD, h = bh % NHEAD;
  const int t = threadIdx.x, w = t >> 6, l = t & 63;
  const int lr = l & 15, lg = l >> 4;

  __shared__ __align__(16) u16 Kl[2][64 * 64];   // K tile [kv][d], swizzled
  __shared__ __align__(16) u16 Vt[2][64 * 64];   // V^T tile [d][kv], swizzled
  __shared__ __align__(16) u16 Pl[8][16][72];    // per-wave P [qrow][kv], pad 72

  const int q0 = qblk * 128;
  const int qw = q0 + w * 16;                    // this wave's first q-row
  const int nkb = 2 * qblk + 2;

  // Q A-frags: lane supplies row lr of the wave's 16-row tile, k = lg*8..+8 per 32-step
  const size_t qoff = ((size_t)(b * T_SEQ + qw + lr)) * QKV_LD + h * 64;
  bhalf8 qf0 = *(const bhalf8*)(qkv + qoff + lg * 8);
  bhalf8 qf1 = *(const bhalf8*)(qkv + qoff + 32 + lg * 8);

  fx4 oacc[4] = {};
  float m_run[4], l_run[4];
  #pragma unroll
  for (int r = 0; r < 4; ++r) { m_run[r] = -3.0e38f; l_run[r] = 0.0f; }

  // --- staging thread mappings (512 threads) ---
  // K: one 16B chunk/thread into linear LDS; source pre-swizzled (G21).
  const int krow = t >> 3;                        // kv row 0..63
  const int kslot = (t & 7) ^ (krow & 7);         // swizzled source 16B slot
  // V: one dwordx4/thread, scatter-transposed with same swizzle on write.
  const int vrow = t >> 3;                        // kv row 0..63
  const int vcol = (t & 7) * 8;                   // d column base
  const size_t kvrow_base = (size_t)(b * T_SEQ) * QKV_LD + 1600 + h * 64;

  int4 vpre;
  // prologue: issue K(0), V(0)
  {
    const size_t ks = kvrow_base + (size_t)krow * QKV_LD + kslot * 8;
    async16(qkv + ks, Kl[0] + t * 8);
    vpre = *(const int4*)(qkv + kvrow_base + (size_t)vrow * QKV_LD + 1600 + vcol);
  }

  for (int kb = 0; kb < nkb; ++kb) {
    const int bsel = kb & 1;
    const int kv0 = kb * 64;
    u16* Klb = Kl[bsel];
    u16* Vtb = Vt[bsel];

    asm volatile("s_waitcnt vmcnt(0)" ::: "memory");  // K(kb) in LDS, V(kb) in regs
    // scatter V(kb) -> Vt[bsel] (transposed, swizzled)
    {
      union { int4 v; u16 u[8]; } vv; vv.v = vpre;
      #pragma unroll
      for (int i = 0; i < 8; ++i) {
        int row = vcol + i;  // d
        Vtb[(row << 6) + (((vrow >> 3) ^ (row & 7)) << 3) + (vrow & 7)] = vv.u[i];
      }
    }
    __syncthreads();  // staging visible; nothing in flight, drain is free

    // issue next tile's loads -- they stay in flight across the whole compute
    if (kb + 1 < nkb) {
      const size_t rb = kvrow_base + (size_t)(kv0 + 64 + krow) * QKV_LD;
      async16(qkv + rb + kslot * 8, Kl[bsel ^ 1] + t * 8);
      vpre = *(const int4*)(qkv + kvrow_base + (size_t)(kv0 + 64 + vrow) * QKV_LD + 1600 + vcol);
    }

    const bool active = (kv0 <= qw + 15);
    if (active) {
      // ---- S = (Q K^T) * scale ----
      float sv[4][4];
      #pragma unroll
      for (int n = 0; n < 4; ++n) {
        bhalf8 k0f = *(const bhalf8*)(Klb + KSWZ(n * 16 + lr, lg));
        bhalf8 k1f = *(const bhalf8*)(Klb + KSWZ(n * 16 + lr, 4 + lg));
        fx4 s = {0.f, 0.f, 0.f, 0.f};
        s = mfma16(qf0, k0f, s);
        s = mfma16(qf1, k1f, s);
        #pragma unroll
        for (int r = 0; r < 4; ++r) sv[n][r] = s[r] * 0.125f;
      }
      if (kv0 + 63 > qw) {  // diagonal overlap: mask kv > q
        #pragma unroll
        for (int n = 0; n < 4; ++n)
          #pragma unroll
          for (int r = 0; r < 4; ++r)
            if (kv0 + n * 16 + lr > qw + lg * 4 + r) sv[n][r] = -1e30f;
      }
      // ---- online softmax (rows live in 16-lane groups; reg r -> row lg*4+r) ----
      #pragma unroll
      for (int r = 0; r < 4; ++r) {
        float mx = fmaxf(fmaxf(sv[0][r], sv[1][r]), fmaxf(sv[2][r], sv[3][r]));
        mx = fmaxf(mx, __shfl_xor(mx, 1));
        mx = fmaxf(mx, __shfl_xor(mx, 2));
        mx = fmaxf(mx, __shfl_xor(mx, 4));
        mx = fmaxf(mx, __shfl_xor(mx, 8));
        float mN = fmaxf(m_run[r], mx);
        float scl = __expf(m_run[r] - mN);
        m_run[r] = mN;
        float rs = 0.f;
        #pragma unroll
        for (int n = 0; n < 4; ++n) {
          float p = __expf(sv[n][r] - mN);
          sv[n][r] = p;
          rs += p;
        }
        rs += __shfl_xor(rs, 1);
        rs += __shfl_xor(rs, 2);
        rs += __shfl_xor(rs, 4);
        rs += __shfl_xor(rs, 8);
        l_run[r] = l_run[r] * scl + rs;
        oacc[0][r] *= scl; oacc[1][r] *= scl; oacc[2][r] *= scl; oacc[3][r] *= scl;
      }
      // ---- P -> bf16 -> per-wave LDS (D-layout write, A-layout read) ----
      #pragma unroll
      for (int n = 0; n < 4; ++n)
        #pragma unroll
        for (int r = 0; r < 4; ++r)
          Pl[w][lg * 4 + r][n * 16 + lr] = f2bf(sv[n][r]);
      asm volatile("s_waitcnt lgkmcnt(0)" ::: "memory");  // cross-lane P visible
      __builtin_amdgcn_sched_barrier(0);                  // guide rule #18
      // ---- O += P V ----
      #pragma unroll
      for (int s = 0; s < 2; ++s) {
        bhalf8 pa = *(const bhalf8*)&Pl[w][lr][s * 32 + lg * 8];
        #pragma unroll
        for (int n = 0; n < 4; ++n) {
          bhalf8 vbf = *(const bhalf8*)(Vtb + KSWZ(n * 16 + lr, s * 4 + lg));
          oacc[n] = mfma16(pa, vbf, oacc[n]);
        }
      }
    }
  }

  // ---- normalize + store [B,T,C] bf16 ----
  const size_t obase = ((size_t)(b * T_SEQ + qw + lg * 4)) * 1600 + h * 64;
  #pragma unroll
  for (int n = 0; n < 4; ++n)
    #pragma unroll
    for (int r = 0; r < 4; ++r) {
      float v = oacc[n][r] / l_run[r];
      out[obase + (size_t)r * 1600 + n * 16 + lr] = f2bf(v);
    }
}

extern "C" void kernel_launch(void* const* d_in, const int* in_sizes, int n_in,
                              void* d_out, int out_size, void* d_ws, size_t ws_size,
                              hipStream_t stream) {
  const float* x     = (const float*)d_in[0];  // [2,2048,1600]
  const float* w_qkv = (const float*)d_in[1];  // [1600,4800]
  const float* b_qkv = (const float*)d_in[2];  // [4800]
  const float* w_out = (const float*)d_in[3];  // [1600,1600]
  const float* b_out = (const float*)d_in[4];  // [1600]
  float* out = (float*)d_out;                  // [2,2048,1600] f32

  constexpr size_t NTOK = 4096;  // B*T
  char* ws = (char*)d_ws;
  size_t off = 0;
  u16* xb    = (u16*)(ws + off); off += NTOK * 1600 * 2;            // x bf16
  u16* wqkvT = (u16*)(ws + off); off += (size_t)QKV_LD * 1600 * 2;  // w_qkv^T bf16 (padded rows)
  u16* woutT = (u16*)(ws + off); off += (size_t)1600 * 1600 * 2;    // w_out^T bf16
  u16* qkvb  = (u16*)(ws + off); off += NTOK * QKV_LD * 2;          // qkv bf16 (padded ldc)
  u16* attnb = (u16*)(ws + off); off += NTOK * 1600 * 2;            // attn out bf16
  (void)ws_size; (void)in_sizes; (void)n_in; (void)out_size;

  cvt_bf16_kernel<<<dim3((unsigned)(NTOK * 1600 / 4 / 256)), dim3(256), 0, stream>>>(
      x, xb, (int)(NTOK * 1600 / 4));
  transp_cvt_kernel<<<dim3(4800 / 32, 1600 / 32), dim3(32, 8), 0, stream>>>(
      w_qkv, wqkvT, 1600, 4800);
  transp_cvt_kernel<<<dim3(1600 / 32, 1600 / 32), dim3(32, 8), 0, stream>>>(
      w_out, woutT, 1600, 1600);
  gemm_bt_kernel<128, false><<<dim3(QKV_LD / 128, NTOK / 128), dim3(256), 0, stream>>>(
      xb, wqkvT, b_qkv, qkvb, 1600, QKV_LD, 4800);
  attn_kernel<<<dim3(T_SEQ / 128, 2 * NHEAD), dim3(512), 0, stream>>>(qkvb, attnb);
  gemm_bt_kernel<64, true><<<dim3(1600 / 64, NTOK / 128), dim3(256), 0, stream>>>(
      attnb, woutT, b_out, out, 1600, 1600, 1600);
}

// Round 5
// 437.365 us; speedup vs baseline: 1.1309x; 1.1309x over previous
//
#include <hip/hip_runtime.h>
#include <cstdint>
#include <cstddef>

typedef unsigned short u16;
typedef __attribute__((ext_vector_type(8))) short bhalf8;   // 8 x bf16 (4 VGPRs)
typedef __attribute__((ext_vector_type(4))) float fx4;      // MFMA 16x16 accumulator
typedef __attribute__((ext_vector_type(4))) unsigned short u16x4;

#define T_SEQ 2048
#define NHEAD 25
#define QKV_LD 4864   // padded 3C row stride (4800 -> 38*128) so 128-wide N-tiles divide evenly

static __device__ __forceinline__ u16 f2bf(float f) {
  union { float f; uint32_t u; } v; v.f = f;
  uint32_t r = (v.u + 0x7FFFu + ((v.u >> 16) & 1u)) >> 16;  // RNE
  return (u16)r;
}

static __device__ __forceinline__ fx4 mfma16(bhalf8 a, bhalf8 b, fx4 c) {
  return __builtin_amdgcn_mfma_f32_16x16x32_bf16(a, b, c, 0, 0, 0);
}

// async global->LDS, 16B per lane. LDS dest: wave-uniform base + lane*16 (linear!).
static __device__ __forceinline__ void async16(const void* g, void* l) {
  __builtin_amdgcn_global_load_lds(
      (__attribute__((address_space(1))) unsigned int*)(void*)g,
      (__attribute__((address_space(3))) unsigned int*)l, 16, 0, 0);
}

// ---------------- convert f32 -> bf16, vectorized (G13) ----------------
__global__ void cvt_bf16_kernel(const float* __restrict__ in, u16* __restrict__ out, int n4) {
  int i = blockIdx.x * 256 + threadIdx.x;
  if (i >= n4) return;
  float4 v = ((const float4*)in)[i];
  u16x4 o;
  o.x = f2bf(v.x); o.y = f2bf(v.y); o.z = f2bf(v.z); o.w = f2bf(v.w);
  ((u16x4*)out)[i] = o;
}

// ------- transpose + convert: in [R][C] f32 -> out [C][R] bf16 (R,C % 32 == 0) -------
__global__ void transp_cvt_kernel(const float* __restrict__ in, u16* __restrict__ out,
                                  int R, int C) {
  __shared__ float tile[32][33];
  int bx = blockIdx.x * 32, by = blockIdx.y * 32;
  int tx = threadIdx.x, ty = threadIdx.y;
  #pragma unroll
  for (int i = 0; i < 32; i += 8)
    tile[ty + i][tx] = in[(size_t)(by + ty + i) * C + bx + tx];
  __syncthreads();
  #pragma unroll
  for (int i = 0; i < 32; i += 8)
    out[(size_t)(bx + ty + i) * R + by + tx] = f2bf(tile[tx][ty + i]);
}

// ---------------- GEMM: C[M,N] = A[M,K] * BT[N,K]^T + bias ----------------
// m97-structure: 128xBN tile, BK=32, 4 waves (2x2), global_load_lds(16B) staging.
// + T1 XCD swizzle (nwg % 8 == 0 for all our launches).
template<int BN, bool OUTF32>
__global__ __launch_bounds__(256)
void gemm_bt_kernel(const u16* __restrict__ A, const u16* __restrict__ BT,
                    const float* __restrict__ bias, void* __restrict__ C,
                    int K, int ldc, int Nreal) {
  constexpr int BM = 128, BK = 32;
  constexpr int NF = BN / 32;                     // frags per wave along N
  constexpr int APASS = (BM * BK) / (256 * 8);    // 2
  constexpr int BPASS = (BN * BK) / (256 * 8);    // 2 (BN=128) or 1 (BN=64)
  __shared__ __align__(16) u16 Al[BM * BK];
  __shared__ __align__(16) u16 Bl[BN * BK];
  const int t = threadIdx.x;
  const int w = t >> 6, l = t & 63, lr = l & 15, lg = l >> 4;
  const int wm = w >> 1, wn = w & 1;

  // XCD-aware swizzle of the linear block id (T1; nwg%8==0 guaranteed here)
  const int nwg = gridDim.x * gridDim.y;
  const int id = blockIdx.y * gridDim.x + blockIdx.x;
  const int qq = nwg >> 3;
  const int swz = (id & 7) * qq + (id >> 3);
  const int bx = swz % gridDim.x, by = swz / gridDim.x;

  const int m0 = by * BM, n0 = bx * BN;

  fx4 acc[4][NF] = {};

  for (int k0 = 0; k0 < K; k0 += BK) {
    #pragma unroll
    for (int p = 0; p < APASS; ++p) {
      int c = t + p * 256;  // 16B chunk id; row = c>>2, col8 = (c&3)*8
      async16(A + (size_t)(m0 + (c >> 2)) * K + k0 + (c & 3) * 8, Al + c * 8);
    }
    #pragma unroll
    for (int p = 0; p < BPASS; ++p) {
      int c = t + p * 256;
      async16(BT + (size_t)(n0 + (c >> 2)) * K + k0 + (c & 3) * 8, Bl + c * 8);
    }
    __syncthreads();  // compiler drains vmcnt before barrier
    bhalf8 af[4], bfr[NF];
    #pragma unroll
    for (int m = 0; m < 4; ++m)
      af[m] = *(const bhalf8*)(Al + (wm * 64 + m * 16 + lr) * BK + lg * 8);
    #pragma unroll
    for (int n = 0; n < NF; ++n)
      bfr[n] = *(const bhalf8*)(Bl + (wn * (BN / 2) + n * 16 + lr) * BK + lg * 8);
    #pragma unroll
    for (int m = 0; m < 4; ++m)
      #pragma unroll
      for (int n = 0; n < NF; ++n)
        acc[m][n] = mfma16(af[m], bfr[n], acc[m][n]);
    __syncthreads();
  }

  // epilogue: C/D layout col=lane&15, row=(lane>>4)*4+reg (m89-verified)
  #pragma unroll
  for (int m = 0; m < 4; ++m)
  #pragma unroll
  for (int n = 0; n < NF; ++n)
  #pragma unroll
  for (int r = 0; r < 4; ++r) {
    int gr = m0 + wm * 64 + m * 16 + lg * 4 + r;
    int gc = n0 + wn * (BN / 2) + n * 16 + lr;
    float bv = (gc < Nreal) ? bias[gc] : 0.0f;
    float v = acc[m][n][r] + bv;
    if constexpr (OUTF32) ((float*)C)[(size_t)gr * ldc + gc] = v;
    else                  ((u16*)C)[(size_t)gr * ldc + gc] = f2bf(v);
  }
}

// ---------------- flash attention, causal, D=64 ----------------
// 8 waves x 16 q-rows = 128 q-rows/block, KBLK=64, double-buffered K/V,
// async16 K staging (XOR-swizzled via pre-swizzled global source),
// reg-staged V with swizzled transpose scatter, ONE barrier per kv-iter.
// Round 3: defer-max softmax (T13, THR=8) + per-lane l accumulation ->
// NO cross-lane shuffles in the common path (they were the serial chain).
// Swizzle: 16B slot s of row r holds data slot (s ^ (r&7)).
#define KSWZ(row, slot) (((row) << 6) + ((((slot)) ^ ((row) & 7)) << 3))

__global__ __launch_bounds__(512, 4)
void attn_kernel(const u16* __restrict__ qkv, u16* __restrict__ out) {
  const int qblk = (gridDim.x - 1) - blockIdx.x;  // big blocks first (causal tail)
  const int bh = blockIdx.y;
  const int b = bh / NHEAD, h = bh % NHEAD;
  const int t = threadIdx.x, w = t >> 6, l = t & 63;
  const int lr = l & 15, lg = l >> 4;

  __shared__ __align__(16) u16 Kl[2][64 * 64];   // K tile [kv][d], swizzled
  __shared__ __align__(16) u16 Vt[2][64 * 64];   // V^T tile [d][kv], swizzled
  __shared__ __align__(16) u16 Pl[8][16][72];    // per-wave P [qrow][kv], pad 72

  const int q0 = qblk * 128;
  const int qw = q0 + w * 16;                    // this wave's first q-row
  const int nkb = 2 * qblk + 2;

  // Q A-frags: lane supplies row lr of the wave's 16-row tile, k = lg*8..+8 per 32-step
  const size_t qoff = ((size_t)(b * T_SEQ + qw + lr)) * QKV_LD + h * 64;
  bhalf8 qf0 = *(const bhalf8*)(qkv + qoff + lg * 8);
  bhalf8 qf1 = *(const bhalf8*)(qkv + qoff + 32 + lg * 8);

  constexpr float KSC = 0.125f * 1.44269504089f;  // scale * log2(e)

  fx4 oacc[4] = {};
  float m_run[4], mk[4], thr[4], l_acc[4];
  #pragma unroll
  for (int r = 0; r < 4; ++r) {
    m_run[r] = -3.0e38f; mk[r] = -3.0e38f; thr[r] = -3.0e38f; l_acc[r] = 0.0f;
  }

  // --- staging thread mappings (512 threads) ---
  // K: one 16B chunk/thread into linear LDS; source pre-swizzled (G21).
  const int krow = t >> 3;                        // kv row 0..63
  const int kslot = (t & 7) ^ (krow & 7);         // swizzled source 16B slot
  // V: one dwordx4/thread, scatter-transposed with same swizzle on write.
  const int vrow = t >> 3;                        // kv row 0..63
  const int vcol = (t & 7) * 8;                   // d column base
  const size_t kvrow_base = (size_t)(b * T_SEQ) * QKV_LD + 1600 + h * 64;

  int4 vpre;
  // prologue: issue K(0), V(0)
  {
    const size_t ks = kvrow_base + (size_t)krow * QKV_LD + kslot * 8;
    async16(qkv + ks, Kl[0] + t * 8);
    vpre = *(const int4*)(qkv + kvrow_base + (size_t)vrow * QKV_LD + 1600 + vcol);
  }

  for (int kb = 0; kb < nkb; ++kb) {
    const int bsel = kb & 1;
    const int kv0 = kb * 64;
    u16* Klb = Kl[bsel];
    u16* Vtb = Vt[bsel];

    asm volatile("s_waitcnt vmcnt(0)" ::: "memory");  // K(kb) in LDS, V(kb) in regs
    // scatter V(kb) -> Vt[bsel] (transposed, swizzled)
    {
      union { int4 v; u16 u[8]; } vv; vv.v = vpre;
      #pragma unroll
      for (int i = 0; i < 8; ++i) {
        int row = vcol + i;  // d
        Vtb[(row << 6) + (((vrow >> 3) ^ (row & 7)) << 3) + (vrow & 7)] = vv.u[i];
      }
    }
    __syncthreads();  // staging visible; nothing in flight, drain is free

    // issue next tile's loads -- they stay in flight across the whole compute
    if (kb + 1 < nkb) {
      const size_t rb = kvrow_base + (size_t)(kv0 + 64 + krow) * QKV_LD;
      async16(qkv + rb + kslot * 8, Kl[bsel ^ 1] + t * 8);
      vpre = *(const int4*)(qkv + kvrow_base + (size_t)(kv0 + 64 + vrow) * QKV_LD + 1600 + vcol);
    }

    const bool active = (kv0 <= qw + 15);
    if (active) {
      // ---- S_raw = Q K^T (unscaled; scale folded into exp2 fma) ----
      float sv[4][4];
      #pragma unroll
      for (int n = 0; n < 4; ++n) {
        bhalf8 k0f = *(const bhalf8*)(Klb + KSWZ(n * 16 + lr, lg));
        bhalf8 k1f = *(const bhalf8*)(Klb + KSWZ(n * 16 + lr, 4 + lg));
        fx4 s = {0.f, 0.f, 0.f, 0.f};
        s = mfma16(qf0, k0f, s);
        s = mfma16(qf1, k1f, s);
        #pragma unroll
        for (int r = 0; r < 4; ++r) sv[n][r] = s[r];
      }
      if (kv0 + 63 > qw) {  // diagonal overlap: mask kv > q
        #pragma unroll
        for (int n = 0; n < 4; ++n)
          #pragma unroll
          for (int r = 0; r < 4; ++r)
            if (kv0 + n * 16 + lr > qw + lg * 4 + r) sv[n][r] = -1e30f;
      }
      // ---- defer-max check: per-lane max vs raw threshold, wave-uniform ballot ----
      float pm[4];
      bool ok = true;
      #pragma unroll
      for (int r = 0; r < 4; ++r) {
        pm[r] = fmaxf(fmaxf(sv[0][r], sv[1][r]), fmaxf(sv[2][r], sv[3][r]));
        ok = ok && (pm[r] <= thr[r]);
      }
      if (!__all(ok)) {
        // slow path (~once per wave): full row-max reduce + rescale state
        #pragma unroll
        for (int r = 0; r < 4; ++r) {
          float mx = pm[r] * 0.125f;
          mx = fmaxf(mx, __shfl_xor(mx, 1));
          mx = fmaxf(mx, __shfl_xor(mx, 2));
          mx = fmaxf(mx, __shfl_xor(mx, 4));
          mx = fmaxf(mx, __shfl_xor(mx, 8));
          float mN = fmaxf(m_run[r], mx);
          float scl = __expf(m_run[r] - mN);   // -inf first time -> 0
          m_run[r] = mN;
          mk[r] = mN * 1.44269504089f;
          thr[r] = 8.0f * mN + 64.0f;          // raw-score form of (m+8)
          l_acc[r] *= scl;
          oacc[0][r] *= scl; oacc[1][r] *= scl; oacc[2][r] *= scl; oacc[3][r] *= scl;
        }
      }
      // ---- common path: P = exp2(S*KSC - mk); per-lane l accumulation ----
      #pragma unroll
      for (int n = 0; n < 4; ++n)
        #pragma unroll
        for (int r = 0; r < 4; ++r) {
          float p = exp2f(fmaf(sv[n][r], KSC, -mk[r]));
          l_acc[r] += p;
          Pl[w][lg * 4 + r][n * 16 + lr] = f2bf(p);
        }
      asm volatile("s_waitcnt lgkmcnt(0)" ::: "memory");  // cross-lane P visible
      __builtin_amdgcn_sched_barrier(0);                  // guide rule #18
      // ---- O += P V ----
      #pragma unroll
      for (int s = 0; s < 2; ++s) {
        bhalf8 pa = *(const bhalf8*)&Pl[w][lr][s * 32 + lg * 8];
        #pragma unroll
        for (int n = 0; n < 4; ++n) {
          bhalf8 vbf = *(const bhalf8*)(Vtb + KSWZ(n * 16 + lr, s * 4 + lg));
          oacc[n] = mfma16(pa, vbf, oacc[n]);
        }
      }
    }
  }

  // ---- epilogue: one cross-lane l reduction, then normalize + store ----
  #pragma unroll
  for (int r = 0; r < 4; ++r) {
    float rs = l_acc[r];
    rs += __shfl_xor(rs, 1);
    rs += __shfl_xor(rs, 2);
    rs += __shfl_xor(rs, 4);
    rs += __shfl_xor(rs, 8);
    l_acc[r] = rs;
  }
  const size_t obase = ((size_t)(b * T_SEQ + qw + lg * 4)) * 1600 + h * 64;
  #pragma unroll
  for (int n = 0; n < 4; ++n)
    #pragma unroll
    for (int r = 0; r < 4; ++r) {
      float v = oacc[n][r] / l_acc[r];
      out[obase + (size_t)r * 1600 + n * 16 + lr] = f2bf(v);
    }
}

extern "C" void kernel_launch(void* const* d_in, const int* in_sizes, int n_in,
                              void* d_out, int out_size, void* d_ws, size_t ws_size,
                              hipStream_t stream) {
  const float* x     = (const float*)d_in[0];  // [2,2048,1600]
  const float* w_qkv = (const float*)d_in[1];  // [1600,4800]
  const float* b_qkv = (const float*)d_in[2];  // [4800]
  const float* w_out = (const float*)d_in[3];  // [1600,1600]
  const float* b_out = (const float*)d_in[4];  // [1600]
  float* out = (float*)d_out;                  // [2,2048,1600] f32

  constexpr size_t NTOK = 4096;  // B*T
  char* ws = (char*)d_ws;
  size_t off = 0;
  u16* xb    = (u16*)(ws + off); off += NTOK * 1600 * 2;            // x bf16
  u16* wqkvT = (u16*)(ws + off); off += (size_t)QKV_LD * 1600 * 2;  // w_qkv^T bf16 (padded rows)
  u16* woutT = (u16*)(ws + off); off += (size_t)1600 * 1600 * 2;    // w_out^T bf16
  u16* qkvb  = (u16*)(ws + off); off += NTOK * QKV_LD * 2;          // qkv bf16 (padded ldc)
  u16* attnb = (u16*)(ws + off); off += NTOK * 1600 * 2;            // attn out bf16
  (void)ws_size; (void)in_sizes; (void)n_in; (void)out_size;

  cvt_bf16_kernel<<<dim3((unsigned)(NTOK * 1600 / 4 / 256)), dim3(256), 0, stream>>>(
      x, xb, (int)(NTOK * 1600 / 4));
  transp_cvt_kernel<<<dim3(4800 / 32, 1600 / 32), dim3(32, 8), 0, stream>>>(
      w_qkv, wqkvT, 1600, 4800);
  transp_cvt_kernel<<<dim3(1600 / 32, 1600 / 32), dim3(32, 8), 0, stream>>>(
      w_out, woutT, 1600, 1600);
  gemm_bt_kernel<128, false><<<dim3(QKV_LD / 128, NTOK / 128), dim3(256), 0, stream>>>(
      xb, wqkvT, b_qkv, qkvb, 1600, QKV_LD, 4800);
  attn_kernel<<<dim3(T_SEQ / 128, 2 * NHEAD), dim3(512), 0, stream>>>(qkvb, attnb);
  gemm_bt_kernel<64, true><<<dim3(1600 / 64, NTOK / 128), dim3(256), 0, stream>>>(
      attnb, woutT, b_out, out, 1600, 1600, 1600);
}